// Round 1
// baseline (527.845 us; speedup 1.0000x reference)
//
#include <hip/hip_runtime.h>
#include <cstdint>

#define NTOT 4096   // 2b rows
#define BHALF 2048  // b
#define D1 4096
#define D2 2048
#define BK 64
#define LDK 68      // padded LDS leading dim (bf16 elems): 136B stride, 8B aligned, conflict-free frag reads
#define TT 32       // 4096/128 tiles per dim

typedef __attribute__((ext_vector_type(8))) short bf16x8;
typedef __attribute__((ext_vector_type(4))) float f32x4;

__device__ __forceinline__ unsigned short f2bf(float f) {
    unsigned int u = __float_as_uint(f);
    u = (u + 0x7fffu + ((u >> 16) & 1u)) >> 16;
    return (unsigned short)u;
}

// ---------------- init: zero colsum arrays + accumulators ----------------
__global__ void init_kernel(float* s1, float* s2, float* acc) {
    int tid = threadIdx.x;
    for (int i = tid; i < 4096; i += 256) s1[i] = 0.f;
    for (int i = tid; i < 2048; i += 256) s2[i] = 0.f;
    if (tid < 8) acc[tid] = 0.f;
}

// ---------------- per-row sum-of-squares (+ optional bf16 convert) ----------------
__global__ void rowsq_kernel(const float* __restrict__ ps, const float* __restrict__ pt,
                             int d, float* __restrict__ sq, float* __restrict__ sumsq,
                             unsigned short* __restrict__ bfout, int dobf) {
    int row = blockIdx.x;
    const float* src = (row < BHALF) ? ps + (size_t)row * d : pt + (size_t)(row - BHALF) * d;
    int tid = threadIdx.x;
    float a = 0.f;
    int nf4 = d >> 2;
    for (int i = tid; i < nf4; i += 256) {
        float4 v = ((const float4*)src)[i];
        a += v.x * v.x + v.y * v.y + v.z * v.z + v.w * v.w;
        if (dobf) {
            ushort4 u;
            u.x = f2bf(v.x); u.y = f2bf(v.y); u.z = f2bf(v.z); u.w = f2bf(v.w);
            *(ushort4*)(bfout + (size_t)row * d + (size_t)i * 4) = u;
        }
    }
    for (int o = 32; o; o >>= 1) a += __shfl_down(a, o);
    __shared__ float sh[4];
    int lane = tid & 63, w = tid >> 6;
    if (lane == 0) sh[w] = a;
    __syncthreads();
    if (tid == 0) {
        float t = sh[0] + sh[1] + sh[2] + sh[3];
        sq[row] = t;
        atomicAdd(sumsq, t);
    }
}

// ---------------- column sums (for ||colsum||^2 closed-form bandwidth) ----------------
__global__ void colsum_kernel(const float* __restrict__ ps, const float* __restrict__ pt,
                              int d, int colchunks, float* __restrict__ s) {
    int cb = blockIdx.x % colchunks;
    int rb = blockIdx.x / colchunks;
    int col = cb * 256 + threadIdx.x;
    int r0 = rb * 256;
    const float* src = (r0 < BHALF) ? ps + (size_t)r0 * d : pt + (size_t)(r0 - BHALF) * d;
    const float* p = src + col;
    float a = 0.f;
    for (int r = 0; r < 256; ++r) a += p[(size_t)r * d];
    atomicAdd(&s[col], a);
}

// ---------------- finalize: bandwidth constants + loss bias ----------------
__global__ void finalize_kernel(const float* __restrict__ s1, const float* __restrict__ s2,
                                float* __restrict__ acc, float* __restrict__ out) {
    int tid = threadIdx.x;
    float a1 = 0.f, a2 = 0.f;
    for (int i = tid; i < 4096; i += 256) { float v = s1[i]; a1 += v * v; }
    for (int i = tid; i < 2048; i += 256) { float v = s2[i]; a2 += v * v; }
    for (int o = 32; o; o >>= 1) { a1 += __shfl_down(a1, o); a2 += __shfl_down(a2, o); }
    __shared__ float sh1[4], sh2[4];
    int lane = tid & 63, w = tid >> 6;
    if (lane == 0) { sh1[w] = a1; sh2[w] = a2; }
    __syncthreads();
    if (tid == 0) {
        double ss1 = (double)sh1[0] + sh1[1] + sh1[2] + sh1[3];
        double ss2 = (double)sh2[0] + sh2[1] + sh2[2] + sh2[3];
        // sum(l2) = 2n*sum(sq) - 2*||colsum||^2
        double S1 = 2.0 * (double)NTOT * (double)acc[0] - 2.0 * ss1;
        double S2 = 2.0 * (double)NTOT * (double)acc[1] - 2.0 * ss2;
        // bw_base = S/((n^2-n)*4); largest bandwidth = 16*bw_base
        // c = log2(e)/(16*bw_base) = (n^2-n)*log2(e)/(4*S)
        const double L2E = 1.4426950408889634;
        double nn = (double)NTOT * (double)(NTOT - 1);
        acc[2] = (float)(nn * L2E / (4.0 * S1));
        acc[3] = (float)(nn * L2E / (4.0 * S2));
        out[0] = 2.0f / (float)(BHALF - 1);
    }
}

// ---------------- fused dual-GEMM + kernel epilogue ----------------
template<bool PRE>
__device__ __forceinline__ void gemm_loop(const void* __restrict__ srcA, const void* __restrict__ srcB,
                                          int d, unsigned short* As, unsigned short* Bs,
                                          f32x4 (&acc)[4][4], int tid, int wm, int wn, int lm, int quad) {
    for (int k0 = 0; k0 < d; k0 += BK) {
        __syncthreads();
        if (PRE) {
            const unsigned short* sa = (const unsigned short*)srcA;
            const unsigned short* sb = (const unsigned short*)srcB;
#pragma unroll
            for (int it = 0; it < 4; ++it) {
                int f = it * 256 + tid;
                int row = f >> 3, kq = f & 7;
                uint4 va = *(const uint4*)(sa + (size_t)row * d + k0 + kq * 8);
                uint4 vb = *(const uint4*)(sb + (size_t)row * d + k0 + kq * 8);
                int off = row * LDK + kq * 8;
                *(uint2*)&As[off] = uint2{va.x, va.y};
                *(uint2*)&As[off + 4] = uint2{va.z, va.w};
                *(uint2*)&Bs[off] = uint2{vb.x, vb.y};
                *(uint2*)&Bs[off + 4] = uint2{vb.z, vb.w};
            }
        } else {
            const float* sa = (const float*)srcA;
            const float* sb = (const float*)srcB;
#pragma unroll
            for (int it = 0; it < 8; ++it) {
                int f = it * 256 + tid;
                int row = f >> 4, kq = f & 15;
                float4 va = *(const float4*)(sa + (size_t)row * d + k0 + kq * 4);
                float4 vb = *(const float4*)(sb + (size_t)row * d + k0 + kq * 4);
                ushort4 ua, ub;
                ua.x = f2bf(va.x); ua.y = f2bf(va.y); ua.z = f2bf(va.z); ua.w = f2bf(va.w);
                ub.x = f2bf(vb.x); ub.y = f2bf(vb.y); ub.z = f2bf(vb.z); ub.w = f2bf(vb.w);
                int off = row * LDK + kq * 4;
                *(ushort4*)&As[off] = ua;
                *(ushort4*)&Bs[off] = ub;
            }
        }
        __syncthreads();
#pragma unroll
        for (int kk = 0; kk < 2; ++kk) {
            bf16x8 a[4], b[4];
#pragma unroll
            for (int mi = 0; mi < 4; ++mi) {
                int off = (wm * 64 + mi * 16 + lm) * LDK + kk * 32 + quad * 8;
                uint2 lo = *(const uint2*)&As[off];
                uint2 hi = *(const uint2*)&As[off + 4];
                union { unsigned int u[4]; bf16x8 v; } cv;
                cv.u[0] = lo.x; cv.u[1] = lo.y; cv.u[2] = hi.x; cv.u[3] = hi.y;
                a[mi] = cv.v;
            }
#pragma unroll
            for (int ni = 0; ni < 4; ++ni) {
                int off = (wn * 64 + ni * 16 + lm) * LDK + kk * 32 + quad * 8;
                uint2 lo = *(const uint2*)&Bs[off];
                uint2 hi = *(const uint2*)&Bs[off + 4];
                union { unsigned int u[4]; bf16x8 v; } cv;
                cv.u[0] = lo.x; cv.u[1] = lo.y; cv.u[2] = hi.x; cv.u[3] = hi.y;
                b[ni] = cv.v;
            }
#pragma unroll
            for (int mi = 0; mi < 4; ++mi)
#pragma unroll
                for (int ni = 0; ni < 4; ++ni)
                    acc[mi][ni] = __builtin_amdgcn_mfma_f32_16x16x32_bf16(a[mi], b[ni], acc[mi][ni], 0, 0, 0);
        }
    }
}

template<bool PRE>
__global__ __launch_bounds__(256, 2) void jmmd_main(
    const float* __restrict__ z1s, const float* __restrict__ z1t,
    const float* __restrict__ z2s, const float* __restrict__ z2t,
    const unsigned short* __restrict__ t1bf, const unsigned short* __restrict__ t2bf,
    const float* __restrict__ sq1, const float* __restrict__ sq2,
    const float* __restrict__ cv, float* __restrict__ out) {
    __shared__ alignas(16) unsigned short As[128 * LDK];
    __shared__ alignas(16) unsigned short Bs[128 * LDK];
    __shared__ float sqi1[128], sqj1[128], sqi2[128], sqj2[128];
    __shared__ float red[4];

    int tid = threadIdx.x;
    // upper-triangular tile decode
    int ti = 0, r = blockIdx.x;
    while (r >= TT - ti) { r -= TT - ti; ++ti; }
    int tj = ti + r;
    int i0 = ti * 128, j0 = tj * 128;

    if (tid < 128) {
        sqi1[tid] = sq1[i0 + tid]; sqj1[tid] = sq1[j0 + tid];
        sqi2[tid] = sq2[i0 + tid]; sqj2[tid] = sq2[j0 + tid];
    }

    int lane = tid & 63, wv = tid >> 6;
    int wm = wv >> 1, wn = wv & 1;
    int lm = lane & 15, quad = lane >> 4;

    f32x4 acc1[4][4] = {};
    f32x4 acc2[4][4] = {};

    const void* a1src; const void* b1src; const void* a2src; const void* b2src;
    if (PRE) {
        a1src = t1bf + (size_t)i0 * D1; b1src = t1bf + (size_t)j0 * D1;
        a2src = t2bf + (size_t)i0 * D2; b2src = t2bf + (size_t)j0 * D2;
    } else {
        a1src = (i0 < BHALF) ? (const void*)(z1s + (size_t)i0 * D1) : (const void*)(z1t + (size_t)(i0 - BHALF) * D1);
        b1src = (j0 < BHALF) ? (const void*)(z1s + (size_t)j0 * D1) : (const void*)(z1t + (size_t)(j0 - BHALF) * D1);
        a2src = (i0 < BHALF) ? (const void*)(z2s + (size_t)i0 * D2) : (const void*)(z2t + (size_t)(i0 - BHALF) * D2);
        b2src = (j0 < BHALF) ? (const void*)(z2s + (size_t)j0 * D2) : (const void*)(z2t + (size_t)(j0 - BHALF) * D2);
    }

    gemm_loop<PRE>(a1src, b1src, D1, As, Bs, acc1, tid, wm, wn, lm, quad);
    gemm_loop<PRE>(a2src, b2src, D2, As, Bs, acc2, tid, wm, wn, lm, quad);

    // epilogue: l2 -> 5-kernel sum via exp + squaring chain, product, reduce
    float c1 = cv[0], c2 = cv[1];
    float local = 0.f;
    bool diag = (ti == tj);
#pragma unroll
    for (int mi = 0; mi < 4; ++mi) {
        int rbase = wm * 64 + mi * 16 + quad * 4;
#pragma unroll
        for (int ni = 0; ni < 4; ++ni) {
            int col = wn * 64 + ni * 16 + lm;
            float sb1 = sqj1[col], sb2 = sqj2[col];
#pragma unroll
            for (int rr = 0; rr < 4; ++rr) {
                int row = rbase + rr;
                float l2a = fmaxf(sqi1[row] + sb1 - 2.f * acc1[mi][ni][rr], 0.f);
                float l2b = fmaxf(sqi2[row] + sb2 - 2.f * acc2[mi][ni][rr], 0.f);
                float t1 = __builtin_amdgcn_exp2f(-l2a * c1);
                float k1 = t1; float u1 = t1 * t1; k1 += u1; u1 *= u1; k1 += u1; u1 *= u1; k1 += u1; u1 *= u1; k1 += u1;
                float t2 = __builtin_amdgcn_exp2f(-l2b * c2);
                float k2 = t2; float u2 = t2 * t2; k2 += u2; u2 *= u2; k2 += u2; u2 *= u2; k2 += u2; u2 *= u2; k2 += u2;
                float v = k1 * k2;
                if (diag && (row == col)) v = 0.f;
                local += v;
            }
        }
    }
    for (int o = 32; o; o >>= 1) local += __shfl_down(local, o);
    if (lane == 0) red[wv] = local;
    __syncthreads();
    if (tid == 0) {
        bool same = (i0 < BHALF) == (j0 < BHALF);
        float w = same ? (1.0f / ((float)BHALF * (float)(BHALF - 1)))
                       : (-1.0f / ((float)BHALF * (float)BHALF));
        if (!diag) w *= 2.f;
        atomicAdd(out, (red[0] + red[1] + red[2] + red[3]) * w);
    }
}

extern "C" void kernel_launch(void* const* d_in, const int* in_sizes, int n_in,
                              void* d_out, int out_size, void* d_ws, size_t ws_size,
                              hipStream_t stream) {
    const float* z1s = (const float*)d_in[0];
    const float* z1t = (const float*)d_in[1];
    const float* z2s = (const float*)d_in[2];
    const float* z2t = (const float*)d_in[3];
    float* out = (float*)d_out;

    float* ws = (float*)d_ws;
    float* sq1 = ws;             // 4096
    float* sq2 = ws + 4096;      // 4096
    float* s1  = ws + 8192;      // 4096
    float* s2  = ws + 12288;     // 2048
    float* acc = ws + 14336;     // [0]=sumsq1 [1]=sumsq2 [2]=c1 [3]=c2
    unsigned short* t1bf = (unsigned short*)(ws + 14344);   // 16B-aligned
    unsigned short* t2bf = t1bf + (size_t)NTOT * D1;
    size_t need = (size_t)14344 * 4 + ((size_t)NTOT * D1 + (size_t)NTOT * D2) * 2;
    bool pre = ws_size >= need;

    init_kernel<<<1, 256, 0, stream>>>(s1, s2, acc);
    rowsq_kernel<<<NTOT, 256, 0, stream>>>(z1s, z1t, D1, sq1, acc + 0, t1bf, pre ? 1 : 0);
    rowsq_kernel<<<NTOT, 256, 0, stream>>>(z2s, z2t, D2, sq2, acc + 1, t2bf, pre ? 1 : 0);
    colsum_kernel<<<(D1 / 256) * (NTOT / 256), 256, 0, stream>>>(z1s, z1t, D1, D1 / 256, s1);
    colsum_kernel<<<(D2 / 256) * (NTOT / 256), 256, 0, stream>>>(z2s, z2t, D2, D2 / 256, s2);
    finalize_kernel<<<1, 256, 0, stream>>>(s1, s2, acc, out);

    int ntiles = TT * (TT + 1) / 2;  // 528
    if (pre)
        jmmd_main<true><<<ntiles, 256, 0, stream>>>(z1s, z1t, z2s, z2t, t1bf, t2bf, sq1, sq2, acc + 2, out);
    else
        jmmd_main<false><<<ntiles, 256, 0, stream>>>(z1s, z1t, z2s, z2t, t1bf, t2bf, sq1, sq2, acc + 2, out);
}

// Round 2
// 498.660 us; speedup vs baseline: 1.0585x; 1.0585x over previous
//
#include <hip/hip_runtime.h>
#include <cstdint>

#define NTOT 4096   // 2b rows
#define BHALF 2048  // b
#define D1 4096
#define D2 2048
#define BK 64
#define LDK 68      // padded LDS leading dim for the fp32 fallback path only
#define TT 32       // 4096/128 tiles per dim

typedef __attribute__((ext_vector_type(8))) short bf16x8;
typedef __attribute__((ext_vector_type(4))) float f32x4;

__device__ __forceinline__ unsigned short f2bf(float f) {
    unsigned int u = __float_as_uint(f);
    u = (u + 0x7fffu + ((u >> 16) & 1u)) >> 16;
    return (unsigned short)u;
}

// async 16B global->LDS DMA (wave-uniform LDS base + lane*16 scatter)
__device__ __forceinline__ void glds16(const unsigned short* g, unsigned short* l) {
    __builtin_amdgcn_global_load_lds(
        (const __attribute__((address_space(1))) void*)(uintptr_t)g,
        (__attribute__((address_space(3))) void*)(uint32_t)(uintptr_t)l,
        16, 0, 0);
}

// ---------------- init: zero colsum arrays + accumulators ----------------
__global__ void init_kernel(float* s1, float* s2, float* acc) {
    int tid = threadIdx.x;
    for (int i = tid; i < 4096; i += 256) s1[i] = 0.f;
    for (int i = tid; i < 2048; i += 256) s2[i] = 0.f;
    if (tid < 8) acc[tid] = 0.f;
}

// ---------------- per-row sum-of-squares (+ optional bf16 convert) ----------------
__global__ void rowsq_kernel(const float* __restrict__ ps, const float* __restrict__ pt,
                             int d, float* __restrict__ sq, float* __restrict__ sumsq,
                             unsigned short* __restrict__ bfout, int dobf) {
    int row = blockIdx.x;
    const float* src = (row < BHALF) ? ps + (size_t)row * d : pt + (size_t)(row - BHALF) * d;
    int tid = threadIdx.x;
    float a = 0.f;
    int nf4 = d >> 2;
    for (int i = tid; i < nf4; i += 256) {
        float4 v = ((const float4*)src)[i];
        a += v.x * v.x + v.y * v.y + v.z * v.z + v.w * v.w;
        if (dobf) {
            ushort4 u;
            u.x = f2bf(v.x); u.y = f2bf(v.y); u.z = f2bf(v.z); u.w = f2bf(v.w);
            *(ushort4*)(bfout + (size_t)row * d + (size_t)i * 4) = u;
        }
    }
    for (int o = 32; o; o >>= 1) a += __shfl_down(a, o);
    __shared__ float sh[4];
    int lane = tid & 63, w = tid >> 6;
    if (lane == 0) sh[w] = a;
    __syncthreads();
    if (tid == 0) {
        float t = sh[0] + sh[1] + sh[2] + sh[3];
        sq[row] = t;
        atomicAdd(sumsq, t);
    }
}

// ---------------- column sums (for ||colsum||^2 closed-form bandwidth) ----------------
__global__ void colsum_kernel(const float* __restrict__ ps, const float* __restrict__ pt,
                              int d, int colchunks, float* __restrict__ s) {
    int cb = blockIdx.x % colchunks;
    int rb = blockIdx.x / colchunks;
    int col = cb * 256 + threadIdx.x;
    int r0 = rb * 256;
    const float* src = (r0 < BHALF) ? ps + (size_t)r0 * d : pt + (size_t)(r0 - BHALF) * d;
    const float* p = src + col;
    float a = 0.f;
    for (int r = 0; r < 256; ++r) a += p[(size_t)r * d];
    atomicAdd(&s[col], a);
}

// ---------------- finalize: bandwidth constants + loss bias ----------------
__global__ void finalize_kernel(const float* __restrict__ s1, const float* __restrict__ s2,
                                float* __restrict__ acc, float* __restrict__ out) {
    int tid = threadIdx.x;
    float a1 = 0.f, a2 = 0.f;
    for (int i = tid; i < 4096; i += 256) { float v = s1[i]; a1 += v * v; }
    for (int i = tid; i < 2048; i += 256) { float v = s2[i]; a2 += v * v; }
    for (int o = 32; o; o >>= 1) { a1 += __shfl_down(a1, o); a2 += __shfl_down(a2, o); }
    __shared__ float sh1[4], sh2[4];
    int lane = tid & 63, w = tid >> 6;
    if (lane == 0) { sh1[w] = a1; sh2[w] = a2; }
    __syncthreads();
    if (tid == 0) {
        double ss1 = (double)sh1[0] + sh1[1] + sh1[2] + sh1[3];
        double ss2 = (double)sh2[0] + sh2[1] + sh2[2] + sh2[3];
        double S1 = 2.0 * (double)NTOT * (double)acc[0] - 2.0 * ss1;
        double S2 = 2.0 * (double)NTOT * (double)acc[1] - 2.0 * ss2;
        const double L2E = 1.4426950408889634;
        double nn = (double)NTOT * (double)(NTOT - 1);
        acc[2] = (float)(nn * L2E / (4.0 * S1));
        acc[3] = (float)(nn * L2E / (4.0 * S2));
        out[0] = 2.0f / (float)(BHALF - 1);
    }
}

// ---------------- PRE path: async-DMA staged GEMM loop (XOR-swizzled LDS) --------
// LDS layout: row r (128 rows), 8 chunks of 16B; logical chunk ql stored at slot
// ql ^ (r&7). DMA writes lane L's 16B at base+L*16 => (row = base_row + (L>>3),
// slot = L&7) => we fetch global chunk (L&7)^(L>>3) so logical layout holds.
__device__ __forceinline__ void gemm_loop_async(const unsigned short* __restrict__ ga,
                                                const unsigned short* __restrict__ gb,
                                                int d, unsigned short* As, unsigned short* Bs,
                                                f32x4 (&acc)[4][4], int wv, int lane,
                                                int wm, int wn, int lm, int quad) {
    int rsub = lane >> 3;              // 0..7
    int ql = (lane & 7) ^ rsub;        // lane-constant source chunk
    const unsigned short* gaL = ga + (size_t)(wv * 32 + rsub) * d + ql * 8;
    const unsigned short* gbL = gb + (size_t)(wv * 32 + rsub) * d + ql * 8;
    unsigned short* AsW = As + wv * 32 * 64;
    unsigned short* BsW = Bs + wv * 32 * 64;
    int sw = lm & 7;
    for (int k0 = 0; k0 < d; k0 += BK) {
        __syncthreads();               // previous compute done; LDS free
#pragma unroll
        for (int i = 0; i < 4; ++i) {
            glds16(gaL + ((size_t)i * 8 * d + k0), AsW + i * 8 * 64);
            glds16(gbL + ((size_t)i * 8 * d + k0), BsW + i * 8 * 64);
        }
        __syncthreads();               // compiler drains vmcnt before barrier -> data ready
#pragma unroll
        for (int kk = 0; kk < 2; ++kk) {
            bf16x8 a[4], b[4];
            int slot = ((kk * 4 + quad) ^ sw) * 8;
#pragma unroll
            for (int mi = 0; mi < 4; ++mi)
                a[mi] = *(const bf16x8*)&As[(wm * 64 + mi * 16 + lm) * 64 + slot];
#pragma unroll
            for (int ni = 0; ni < 4; ++ni)
                b[ni] = *(const bf16x8*)&Bs[(wn * 64 + ni * 16 + lm) * 64 + slot];
#pragma unroll
            for (int mi = 0; mi < 4; ++mi)
#pragma unroll
                for (int ni = 0; ni < 4; ++ni)
                    acc[mi][ni] = __builtin_amdgcn_mfma_f32_16x16x32_bf16(a[mi], b[ni], acc[mi][ni], 0, 0, 0);
        }
    }
}

// ---------------- fallback path: fp32 loads + VGPR roundtrip (padded LDS) --------
__device__ __forceinline__ void gemm_loop_f32(const void* __restrict__ srcA, const void* __restrict__ srcB,
                                              int d, unsigned short* As, unsigned short* Bs,
                                              f32x4 (&acc)[4][4], int tid, int wm, int wn, int lm, int quad) {
    for (int k0 = 0; k0 < d; k0 += BK) {
        __syncthreads();
        const float* sa = (const float*)srcA;
        const float* sb = (const float*)srcB;
#pragma unroll
        for (int it = 0; it < 8; ++it) {
            int f = it * 256 + tid;
            int row = f >> 4, kq = f & 15;
            float4 va = *(const float4*)(sa + (size_t)row * d + k0 + kq * 4);
            float4 vb = *(const float4*)(sb + (size_t)row * d + k0 + kq * 4);
            ushort4 ua, ub;
            ua.x = f2bf(va.x); ua.y = f2bf(va.y); ua.z = f2bf(va.z); ua.w = f2bf(va.w);
            ub.x = f2bf(vb.x); ub.y = f2bf(vb.y); ub.z = f2bf(vb.z); ub.w = f2bf(vb.w);
            int off = row * LDK + kq * 4;
            *(ushort4*)&As[off] = ua;
            *(ushort4*)&Bs[off] = ub;
        }
        __syncthreads();
#pragma unroll
        for (int kk = 0; kk < 2; ++kk) {
            bf16x8 a[4], b[4];
#pragma unroll
            for (int mi = 0; mi < 4; ++mi) {
                int off = (wm * 64 + mi * 16 + lm) * LDK + kk * 32 + quad * 8;
                uint2 lo = *(const uint2*)&As[off];
                uint2 hi = *(const uint2*)&As[off + 4];
                union { unsigned int u[4]; bf16x8 v; } cv;
                cv.u[0] = lo.x; cv.u[1] = lo.y; cv.u[2] = hi.x; cv.u[3] = hi.y;
                a[mi] = cv.v;
            }
#pragma unroll
            for (int ni = 0; ni < 4; ++ni) {
                int off = (wn * 64 + ni * 16 + lm) * LDK + kk * 32 + quad * 8;
                uint2 lo = *(const uint2*)&Bs[off];
                uint2 hi = *(const uint2*)&Bs[off + 4];
                union { unsigned int u[4]; bf16x8 v; } cv;
                cv.u[0] = lo.x; cv.u[1] = lo.y; cv.u[2] = hi.x; cv.u[3] = hi.y;
                b[ni] = cv.v;
            }
#pragma unroll
            for (int mi = 0; mi < 4; ++mi)
#pragma unroll
                for (int ni = 0; ni < 4; ++ni)
                    acc[mi][ni] = __builtin_amdgcn_mfma_f32_16x16x32_bf16(a[mi], b[ni], acc[mi][ni], 0, 0, 0);
        }
    }
}

template<bool PRE>
__global__ __launch_bounds__(256, 2) void jmmd_main(
    const float* __restrict__ z1s, const float* __restrict__ z1t,
    const float* __restrict__ z2s, const float* __restrict__ z2t,
    const unsigned short* __restrict__ t1bf, const unsigned short* __restrict__ t2bf,
    const float* __restrict__ sq1, const float* __restrict__ sq2,
    const float* __restrict__ cv, float* __restrict__ out) {
    __shared__ alignas(16) unsigned short As[128 * LDK];
    __shared__ alignas(16) unsigned short Bs[128 * LDK];
    __shared__ float sqi1[128], sqj1[128], sqi2[128], sqj2[128];
    __shared__ float red[4];

    int tid = threadIdx.x;
    // upper-triangular tile decode
    int ti = 0, r = blockIdx.x;
    while (r >= TT - ti) { r -= TT - ti; ++ti; }
    int tj = ti + r;
    int i0 = ti * 128, j0 = tj * 128;

    if (tid < 128) {
        sqi1[tid] = sq1[i0 + tid]; sqj1[tid] = sq1[j0 + tid];
        sqi2[tid] = sq2[i0 + tid]; sqj2[tid] = sq2[j0 + tid];
    }

    int lane = tid & 63, wv = tid >> 6;
    int wm = wv >> 1, wn = wv & 1;
    int lm = lane & 15, quad = lane >> 4;

    f32x4 acc1[4][4] = {};
    f32x4 acc2[4][4] = {};

    if (PRE) {
        const unsigned short* a1 = t1bf + (size_t)i0 * D1;
        const unsigned short* b1 = t1bf + (size_t)j0 * D1;
        const unsigned short* a2 = t2bf + (size_t)i0 * D2;
        const unsigned short* b2 = t2bf + (size_t)j0 * D2;
        gemm_loop_async(a1, b1, D1, As, Bs, acc1, wv, lane, wm, wn, lm, quad);
        gemm_loop_async(a2, b2, D2, As, Bs, acc2, wv, lane, wm, wn, lm, quad);
    } else {
        const void* a1src = (i0 < BHALF) ? (const void*)(z1s + (size_t)i0 * D1) : (const void*)(z1t + (size_t)(i0 - BHALF) * D1);
        const void* b1src = (j0 < BHALF) ? (const void*)(z1s + (size_t)j0 * D1) : (const void*)(z1t + (size_t)(j0 - BHALF) * D1);
        const void* a2src = (i0 < BHALF) ? (const void*)(z2s + (size_t)i0 * D2) : (const void*)(z2t + (size_t)(i0 - BHALF) * D2);
        const void* b2src = (j0 < BHALF) ? (const void*)(z2s + (size_t)j0 * D2) : (const void*)(z2t + (size_t)(j0 - BHALF) * D2);
        gemm_loop_f32(a1src, b1src, D1, As, Bs, acc1, tid, wm, wn, lm, quad);
        gemm_loop_f32(a2src, b2src, D2, As, Bs, acc2, tid, wm, wn, lm, quad);
    }

    // epilogue: l2 -> 5-kernel sum via exp + squaring chain, product, reduce
    float c1 = cv[0], c2 = cv[1];
    float local = 0.f;
    bool diag = (ti == tj);
#pragma unroll
    for (int mi = 0; mi < 4; ++mi) {
        int rbase = wm * 64 + mi * 16 + quad * 4;
#pragma unroll
        for (int ni = 0; ni < 4; ++ni) {
            int col = wn * 64 + ni * 16 + lm;
            float sb1 = sqj1[col], sb2 = sqj2[col];
#pragma unroll
            for (int rr = 0; rr < 4; ++rr) {
                int row = rbase + rr;
                float l2a = fmaxf(sqi1[row] + sb1 - 2.f * acc1[mi][ni][rr], 0.f);
                float l2b = fmaxf(sqi2[row] + sb2 - 2.f * acc2[mi][ni][rr], 0.f);
                float t1 = __builtin_amdgcn_exp2f(-l2a * c1);
                float k1 = t1; float u1 = t1 * t1; k1 += u1; u1 *= u1; k1 += u1; u1 *= u1; k1 += u1; u1 *= u1; k1 += u1;
                float t2 = __builtin_amdgcn_exp2f(-l2b * c2);
                float k2 = t2; float u2 = t2 * t2; k2 += u2; u2 *= u2; k2 += u2; u2 *= u2; k2 += u2; u2 *= u2; k2 += u2;
                float v = k1 * k2;
                if (diag && (row == col)) v = 0.f;
                local += v;
            }
        }
    }
    for (int o = 32; o; o >>= 1) local += __shfl_down(local, o);
    if (lane == 0) red[wv] = local;
    __syncthreads();
    if (tid == 0) {
        bool same = (i0 < BHALF) == (j0 < BHALF);
        float w = same ? (1.0f / ((float)BHALF * (float)(BHALF - 1)))
                       : (-1.0f / ((float)BHALF * (float)BHALF));
        if (!diag) w *= 2.f;
        atomicAdd(out, (red[0] + red[1] + red[2] + red[3]) * w);
    }
}

extern "C" void kernel_launch(void* const* d_in, const int* in_sizes, int n_in,
                              void* d_out, int out_size, void* d_ws, size_t ws_size,
                              hipStream_t stream) {
    const float* z1s = (const float*)d_in[0];
    const float* z1t = (const float*)d_in[1];
    const float* z2s = (const float*)d_in[2];
    const float* z2t = (const float*)d_in[3];
    float* out = (float*)d_out;

    float* ws = (float*)d_ws;
    float* sq1 = ws;             // 4096
    float* sq2 = ws + 4096;      // 4096
    float* s1  = ws + 8192;      // 4096
    float* s2  = ws + 12288;     // 2048
    float* acc = ws + 14336;     // [0]=sumsq1 [1]=sumsq2 [2]=c1 [3]=c2
    unsigned short* t1bf = (unsigned short*)(ws + 14344);   // 16B-aligned
    unsigned short* t2bf = t1bf + (size_t)NTOT * D1;
    size_t need = (size_t)14344 * 4 + ((size_t)NTOT * D1 + (size_t)NTOT * D2) * 2;
    bool pre = ws_size >= need;

    init_kernel<<<1, 256, 0, stream>>>(s1, s2, acc);
    rowsq_kernel<<<NTOT, 256, 0, stream>>>(z1s, z1t, D1, sq1, acc + 0, t1bf, pre ? 1 : 0);
    rowsq_kernel<<<NTOT, 256, 0, stream>>>(z2s, z2t, D2, sq2, acc + 1, t2bf, pre ? 1 : 0);
    colsum_kernel<<<(D1 / 256) * (NTOT / 256), 256, 0, stream>>>(z1s, z1t, D1, D1 / 256, s1);
    colsum_kernel<<<(D2 / 256) * (NTOT / 256), 256, 0, stream>>>(z2s, z2t, D2, D2 / 256, s2);
    finalize_kernel<<<1, 256, 0, stream>>>(s1, s2, acc, out);

    int ntiles = TT * (TT + 1) / 2;  // 528
    if (pre)
        jmmd_main<true><<<ntiles, 256, 0, stream>>>(z1s, z1t, z2s, z2t, t1bf, t2bf, sq1, sq2, acc + 2, out);
    else
        jmmd_main<false><<<ntiles, 256, 0, stream>>>(z1s, z1t, z2s, z2t, t1bf, t2bf, sq1, sq2, acc + 2, out);
}

// Round 3
// 398.523 us; speedup vs baseline: 1.3245x; 1.2513x over previous
//
#include <hip/hip_runtime.h>
#include <cstdint>

#define NTOT 4096   // 2b rows
#define BHALF 2048  // b
#define D1 4096
#define D2 2048
#define BK 64
#define TT 32       // 4096/128 tiles per dim
#define NTILES 528  // TT*(TT+1)/2

typedef __attribute__((ext_vector_type(8))) short bf16x8;
typedef __attribute__((ext_vector_type(4))) float f32x4;

__device__ __forceinline__ unsigned short f2bf(float f) {
    unsigned int u = __float_as_uint(f);
    u = (u + 0x7fffu + ((u >> 16) & 1u)) >> 16;
    return (unsigned short)u;
}

// async 16B global->LDS DMA (wave-uniform LDS base + lane*16 scatter)
__device__ __forceinline__ void glds16(const unsigned short* g, unsigned short* l) {
    __builtin_amdgcn_global_load_lds(
        (const __attribute__((address_space(1))) void*)(uintptr_t)g,
        (__attribute__((address_space(3))) void*)(uint32_t)(uintptr_t)l,
        16, 0, 0);
}

// ---------------- init: zero colsum arrays ----------------
__global__ void init_kernel(float* s1, float* s2) {
    int tid = threadIdx.x;
    for (int i = tid; i < 4096; i += 256) s1[i] = 0.f;
    for (int i = tid; i < 2048; i += 256) s2[i] = 0.f;
}

// ---------------- prep: per-row sumsq + bf16 convert, both matrices ----------------
__global__ void prep_kernel(const float* __restrict__ z1s, const float* __restrict__ z1t,
                            const float* __restrict__ z2s, const float* __restrict__ z2t,
                            float* __restrict__ sq1, float* __restrict__ sq2,
                            unsigned short* __restrict__ t1bf, unsigned short* __restrict__ t2bf) {
    int bid = blockIdx.x;
    int which = bid >> 12;     // 0: matrix1 (d=4096), 1: matrix2 (d=2048)
    int row = bid & 4095;
    int d = which ? D2 : D1;
    const float* s_ = which ? z2s : z1s;
    const float* t_ = which ? z2t : z1t;
    const float* src = (row < BHALF) ? s_ + (size_t)row * d : t_ + (size_t)(row - BHALF) * d;
    unsigned short* dst = (which ? t2bf : t1bf) + (size_t)row * d;
    float* sq = which ? sq2 : sq1;
    int tid = threadIdx.x;
    float a = 0.f;
    int nf4 = d >> 2;
    for (int i = tid; i < nf4; i += 256) {
        float4 v = ((const float4*)src)[i];
        a += v.x * v.x + v.y * v.y + v.z * v.z + v.w * v.w;
        ushort4 u;
        u.x = f2bf(v.x); u.y = f2bf(v.y); u.z = f2bf(v.z); u.w = f2bf(v.w);
        ((ushort4*)dst)[i] = u;
    }
    for (int o = 32; o; o >>= 1) a += __shfl_down(a, o);
    __shared__ float sh[4];
    int lane = tid & 63, w = tid >> 6;
    if (lane == 0) sh[w] = a;
    __syncthreads();
    if (tid == 0) sq[row] = sh[0] + sh[1] + sh[2] + sh[3];
}

// ---------------- column sums from bf16 copies (bandwidth term only) ----------------
// blocks 0..63: matrix1 (4 colchunks x 16 row panels); 64..95: matrix2 (2 x 16)
__global__ void colsum_bf_kernel(const unsigned short* __restrict__ t1bf,
                                 const unsigned short* __restrict__ t2bf,
                                 float* __restrict__ s1, float* __restrict__ s2) {
    int bid = blockIdx.x;
    int which = bid >= 64;
    int local = which ? bid - 64 : bid;
    int d = which ? D2 : D1;
    int colchunks = d >> 10;
    int cb = local % colchunks, rb = local / colchunks;
    const unsigned short* base = which ? t2bf : t1bf;
    float* s = which ? s2 : s1;
    int col = (cb << 10) + threadIdx.x * 4;
    int r0 = rb * 256;
    float ax = 0.f, ay = 0.f, az = 0.f, aw = 0.f;
    const unsigned short* p = base + (size_t)r0 * d + col;
    for (int r = 0; r < 256; ++r) {
        ushort4 u = *(const ushort4*)(p + (size_t)r * d);
        ax += __uint_as_float((unsigned)u.x << 16);
        ay += __uint_as_float((unsigned)u.y << 16);
        az += __uint_as_float((unsigned)u.z << 16);
        aw += __uint_as_float((unsigned)u.w << 16);
    }
    atomicAdd(&s[col], ax); atomicAdd(&s[col + 1], ay);
    atomicAdd(&s[col + 2], az); atomicAdd(&s[col + 3], aw);
}

// ---------------- finalize: bandwidth constants + loss bias ----------------
__global__ void finalize_kernel(const float* __restrict__ s1, const float* __restrict__ s2,
                                const float* __restrict__ sq1, const float* __restrict__ sq2,
                                float* __restrict__ acc, float* __restrict__ out) {
    int tid = threadIdx.x;
    float a1 = 0.f, a2 = 0.f, q1 = 0.f, q2 = 0.f;
    for (int i = tid; i < 4096; i += 256) { float v = s1[i]; a1 += v * v; q1 += sq1[i]; q2 += sq2[i]; }
    for (int i = tid; i < 2048; i += 256) { float v = s2[i]; a2 += v * v; }
    for (int o = 32; o; o >>= 1) {
        a1 += __shfl_down(a1, o); a2 += __shfl_down(a2, o);
        q1 += __shfl_down(q1, o); q2 += __shfl_down(q2, o);
    }
    __shared__ float sh[4][4];
    int lane = tid & 63, w = tid >> 6;
    if (lane == 0) { sh[0][w] = a1; sh[1][w] = a2; sh[2][w] = q1; sh[3][w] = q2; }
    __syncthreads();
    if (tid == 0) {
        double ss1 = (double)sh[0][0] + sh[0][1] + sh[0][2] + sh[0][3];
        double ss2 = (double)sh[1][0] + sh[1][1] + sh[1][2] + sh[1][3];
        double t1 = (double)sh[2][0] + sh[2][1] + sh[2][2] + sh[2][3];
        double t2 = (double)sh[3][0] + sh[3][1] + sh[3][2] + sh[3][3];
        double S1 = 2.0 * (double)NTOT * t1 - 2.0 * ss1;
        double S2 = 2.0 * (double)NTOT * t2 - 2.0 * ss2;
        const double L2E = 1.4426950408889634;
        double nn = (double)NTOT * (double)(NTOT - 1);
        acc[2] = (float)(nn * L2E / (4.0 * S1));
        acc[3] = (float)(nn * L2E / (4.0 * S2));
        out[0] = 2.0f / (float)(BHALF - 1);
    }
}

// ---------------- async-DMA staged GEMM loop (XOR-swizzled LDS) --------
__device__ __forceinline__ void gemm_loop_async(const unsigned short* __restrict__ ga,
                                                const unsigned short* __restrict__ gb,
                                                int d, unsigned short* As, unsigned short* Bs,
                                                f32x4 (&acc)[4][4], int wv, int lane,
                                                int wm, int wn, int lm, int quad) {
    int rsub = lane >> 3;              // 0..7
    int ql = (lane & 7) ^ rsub;        // lane-constant source chunk
    const unsigned short* gaL = ga + (size_t)(wv * 32 + rsub) * d + ql * 8;
    const unsigned short* gbL = gb + (size_t)(wv * 32 + rsub) * d + ql * 8;
    unsigned short* AsW = As + wv * 32 * 64;
    unsigned short* BsW = Bs + wv * 32 * 64;
    int sw = lm & 7;
    for (int k0 = 0; k0 < d; k0 += BK) {
        __syncthreads();
#pragma unroll
        for (int i = 0; i < 4; ++i) {
            glds16(gaL + ((size_t)i * 8 * d + k0), AsW + i * 8 * 64);
            glds16(gbL + ((size_t)i * 8 * d + k0), BsW + i * 8 * 64);
        }
        __syncthreads();
#pragma unroll
        for (int kk = 0; kk < 2; ++kk) {
            bf16x8 a[4], b[4];
            int slot = ((kk * 4 + quad) ^ sw) * 8;
#pragma unroll
            for (int mi = 0; mi < 4; ++mi)
                a[mi] = *(const bf16x8*)&As[(wm * 64 + mi * 16 + lm) * 64 + slot];
#pragma unroll
            for (int ni = 0; ni < 4; ++ni)
                b[ni] = *(const bf16x8*)&Bs[(wn * 64 + ni * 16 + lm) * 64 + slot];
#pragma unroll
            for (int mi = 0; mi < 4; ++mi)
#pragma unroll
                for (int ni = 0; ni < 4; ++ni)
                    acc[mi][ni] = __builtin_amdgcn_mfma_f32_16x16x32_bf16(a[mi], b[ni], acc[mi][ni], 0, 0, 0);
        }
    }
}

// ---------------- Gram kernel: 1056 blocks = 528 tiles x {GEMM1, GEMM2} ----------
__global__ __launch_bounds__(256, 4) void gram_kernel(
    const unsigned short* __restrict__ t1bf, const unsigned short* __restrict__ t2bf,
    float* __restrict__ G1, float* __restrict__ G2) {
    __shared__ alignas(16) unsigned short As[128 * 64];
    __shared__ alignas(16) unsigned short Bs[128 * 64];
    int lid = blockIdx.x;
    // XCD-contiguous remap (assumes round-robin lid%8 -> XCD): each XCD covers a
    // contiguous lin range; lin pairs tile t's two GEMMs adjacently (load balance).
    int lin = (lid & 7) * 132 + (lid >> 3);
    int t = lin >> 1, which = lin & 1;
    int ti = 0, r = t;
    while (r >= TT - ti) { r -= TT - ti; ++ti; }
    int tj = ti + r;
    int i0 = ti * 128, j0 = tj * 128;
    int d = which ? D2 : D1;
    const unsigned short* base = which ? t2bf : t1bf;
    float* G = (which ? G2 : G1) + (size_t)t * 16384;

    int tid = threadIdx.x, lane = tid & 63, wv = tid >> 6;
    int wm = wv >> 1, wn = wv & 1, lm = lane & 15, quad = lane >> 4;
    f32x4 acc[4][4] = {};
    gemm_loop_async(base + (size_t)i0 * d, base + (size_t)j0 * d, d, As, Bs, acc,
                    wv, lane, wm, wn, lm, quad);
#pragma unroll
    for (int mi = 0; mi < 4; ++mi)
#pragma unroll
        for (int ni = 0; ni < 4; ++ni)
#pragma unroll
            for (int rr = 0; rr < 4; ++rr)
                G[(size_t)(wm * 64 + mi * 16 + quad * 4 + rr) * 128 + wn * 64 + ni * 16 + lm] =
                    acc[mi][ni][rr];
}

// ---------------- epilogue: read Grams, 5-kernel sum, product, weighted reduce ----
__global__ __launch_bounds__(256, 4) void epi_kernel(
    const float* __restrict__ G1, const float* __restrict__ G2,
    const float* __restrict__ sq1, const float* __restrict__ sq2,
    const float* __restrict__ cv, float* __restrict__ out) {
    __shared__ float sqi1[128], sqj1[128], sqi2[128], sqj2[128];
    __shared__ float red[4];
    int t = blockIdx.x;
    int ti = 0, r = t;
    while (r >= TT - ti) { r -= TT - ti; ++ti; }
    int tj = ti + r;
    int i0 = ti * 128, j0 = tj * 128;
    int tid = threadIdx.x;
    if (tid < 128) {
        sqi1[tid] = sq1[i0 + tid]; sqj1[tid] = sq1[j0 + tid];
        sqi2[tid] = sq2[i0 + tid]; sqj2[tid] = sq2[j0 + tid];
    }
    __syncthreads();
    float c1 = cv[0], c2 = cv[1];
    const float4* g1 = (const float4*)(G1 + (size_t)t * 16384);
    const float4* g2 = (const float4*)(G2 + (size_t)t * 16384);
    bool diag = (ti == tj);
    float local = 0.f;
#pragma unroll 4
    for (int it = 0; it < 16; ++it) {
        int e4 = it * 256 + tid;
        int row = e4 >> 5, col = (e4 & 31) * 4;
        float4 a = g1[e4], b = g2[e4];
        float si1 = sqi1[row], si2 = sqi2[row];
        float ax[4] = {a.x, a.y, a.z, a.w}, bx[4] = {b.x, b.y, b.z, b.w};
#pragma unroll
        for (int j = 0; j < 4; ++j) {
            float l2a = fmaxf(si1 + sqj1[col + j] - 2.f * ax[j], 0.f);
            float l2b = fmaxf(si2 + sqj2[col + j] - 2.f * bx[j], 0.f);
            float t1 = __builtin_amdgcn_exp2f(-l2a * c1);
            float k1 = t1; float u1 = t1 * t1; k1 += u1; u1 *= u1; k1 += u1; u1 *= u1; k1 += u1; u1 *= u1; k1 += u1;
            float t2 = __builtin_amdgcn_exp2f(-l2b * c2);
            float k2 = t2; float u2 = t2 * t2; k2 += u2; u2 *= u2; k2 += u2; u2 *= u2; k2 += u2; u2 *= u2; k2 += u2;
            float v = k1 * k2;
            if (diag && (row == col + j)) v = 0.f;
            local += v;
        }
    }
    for (int o = 32; o; o >>= 1) local += __shfl_down(local, o);
    int lane = tid & 63, wv = tid >> 6;
    if (lane == 0) red[wv] = local;
    __syncthreads();
    if (tid == 0) {
        bool same = (i0 < BHALF) == (j0 < BHALF);
        float w = same ? (1.0f / ((float)BHALF * (float)(BHALF - 1)))
                       : (-1.0f / ((float)BHALF * (float)BHALF));
        if (!diag) w *= 2.f;
        atomicAdd(out, (red[0] + red[1] + red[2] + red[3]) * w);
    }
}

// ---------------- fallback: fused dual-GEMM (used when ws too small for Grams) ----
__global__ __launch_bounds__(256, 2) void jmmd_fused(
    const unsigned short* __restrict__ t1bf, const unsigned short* __restrict__ t2bf,
    const float* __restrict__ sq1, const float* __restrict__ sq2,
    const float* __restrict__ cv, float* __restrict__ out) {
    __shared__ alignas(16) unsigned short As[128 * 64];
    __shared__ alignas(16) unsigned short Bs[128 * 64];
    __shared__ float sqi1[128], sqj1[128], sqi2[128], sqj2[128];
    __shared__ float red[4];
    int tid = threadIdx.x;
    int ti = 0, r = blockIdx.x;
    while (r >= TT - ti) { r -= TT - ti; ++ti; }
    int tj = ti + r;
    int i0 = ti * 128, j0 = tj * 128;
    if (tid < 128) {
        sqi1[tid] = sq1[i0 + tid]; sqj1[tid] = sq1[j0 + tid];
        sqi2[tid] = sq2[i0 + tid]; sqj2[tid] = sq2[j0 + tid];
    }
    int lane = tid & 63, wv = tid >> 6;
    int wm = wv >> 1, wn = wv & 1, lm = lane & 15, quad = lane >> 4;
    f32x4 acc1[4][4] = {};
    f32x4 acc2[4][4] = {};
    gemm_loop_async(t1bf + (size_t)i0 * D1, t1bf + (size_t)j0 * D1, D1, As, Bs, acc1, wv, lane, wm, wn, lm, quad);
    gemm_loop_async(t2bf + (size_t)i0 * D2, t2bf + (size_t)j0 * D2, D2, As, Bs, acc2, wv, lane, wm, wn, lm, quad);
    float c1 = cv[0], c2 = cv[1];
    float local = 0.f;
    bool diag = (ti == tj);
#pragma unroll
    for (int mi = 0; mi < 4; ++mi) {
        int rbase = wm * 64 + mi * 16 + quad * 4;
#pragma unroll
        for (int ni = 0; ni < 4; ++ni) {
            int col = wn * 64 + ni * 16 + lm;
            float sb1 = sqj1[col], sb2 = sqj2[col];
#pragma unroll
            for (int rr = 0; rr < 4; ++rr) {
                int row = rbase + rr;
                float l2a = fmaxf(sqi1[row] + sb1 - 2.f * acc1[mi][ni][rr], 0.f);
                float l2b = fmaxf(sqi2[row] + sb2 - 2.f * acc2[mi][ni][rr], 0.f);
                float t1 = __builtin_amdgcn_exp2f(-l2a * c1);
                float k1 = t1; float u1 = t1 * t1; k1 += u1; u1 *= u1; k1 += u1; u1 *= u1; k1 += u1; u1 *= u1; k1 += u1;
                float t2 = __builtin_amdgcn_exp2f(-l2b * c2);
                float k2 = t2; float u2 = t2 * t2; k2 += u2; u2 *= u2; k2 += u2; u2 *= u2; k2 += u2; u2 *= u2; k2 += u2;
                float v = k1 * k2;
                if (diag && (row == col)) v = 0.f;
                local += v;
            }
        }
    }
    for (int o = 32; o; o >>= 1) local += __shfl_down(local, o);
    if (lane == 0) red[wv] = local;
    __syncthreads();
    if (tid == 0) {
        bool same = (i0 < BHALF) == (j0 < BHALF);
        float w = same ? (1.0f / ((float)BHALF * (float)(BHALF - 1)))
                       : (-1.0f / ((float)BHALF * (float)BHALF));
        if (!diag) w *= 2.f;
        atomicAdd(out, (red[0] + red[1] + red[2] + red[3]) * w);
    }
}

extern "C" void kernel_launch(void* const* d_in, const int* in_sizes, int n_in,
                              void* d_out, int out_size, void* d_ws, size_t ws_size,
                              hipStream_t stream) {
    const float* z1s = (const float*)d_in[0];
    const float* z1t = (const float*)d_in[1];
    const float* z2s = (const float*)d_in[2];
    const float* z2t = (const float*)d_in[3];
    float* out = (float*)d_out;

    float* ws = (float*)d_ws;
    float* sq1 = ws;              // 4096
    float* sq2 = ws + 4096;       // 4096
    float* s1  = ws + 8192;       // 4096
    float* s2  = ws + 12288;      // 2048
    float* acc = ws + 14336;      // [2]=c1 [3]=c2
    unsigned short* t1bf = (unsigned short*)(ws + 14344);   // 16B-aligned
    unsigned short* t2bf = t1bf + (size_t)NTOT * D1;
    float* G1 = (float*)(t2bf + (size_t)NTOT * D2);
    float* G2 = G1 + (size_t)NTILES * 16384;
    size_t need_big = (size_t)14344 * 4
                    + ((size_t)NTOT * D1 + (size_t)NTOT * D2) * 2
                    + (size_t)NTILES * 16384 * 2 * 4;

    init_kernel<<<1, 256, 0, stream>>>(s1, s2);
    prep_kernel<<<8192, 256, 0, stream>>>(z1s, z1t, z2s, z2t, sq1, sq2, t1bf, t2bf);
    colsum_bf_kernel<<<96, 256, 0, stream>>>(t1bf, t2bf, s1, s2);
    finalize_kernel<<<1, 256, 0, stream>>>(s1, s2, sq1, sq2, acc, out);

    if (ws_size >= need_big) {
        gram_kernel<<<1056, 256, 0, stream>>>(t1bf, t2bf, G1, G2);
        epi_kernel<<<NTILES, 256, 0, stream>>>(G1, G2, sq1, sq2, acc + 2, out);
    } else {
        jmmd_fused<<<NTILES, 256, 0, stream>>>(t1bf, t2bf, sq1, sq2, acc + 2, out);
    }
}